// Round 5
// baseline (800.939 us; speedup 1.0000x reference)
//
#include <hip/hip_runtime.h>

typedef __bf16 bf16x8 __attribute__((ext_vector_type(8)));
typedef float  f32x4  __attribute__((ext_vector_type(4)));
typedef unsigned short us8 __attribute__((ext_vector_type(8)));

__device__ __forceinline__ unsigned short f2bf(float f) {
    union { float f; unsigned u; } c; c.f = f;
    unsigned u = c.u;
    u += 0x7FFFu + ((u >> 16) & 1u);   // RNE; inputs finite
    return (unsigned short)(u >> 16);
}
__device__ __forceinline__ float sigf(float v) { return 1.0f / (1.0f + __expf(-v)); }

// -------- weight pre-transform: OIHW f32 -> [tap][co][ci] bf16 (16 KB/tap) ----
__global__ void __launch_bounds__(256) wxform(const float* __restrict__ W,
                                              unsigned short* __restrict__ wpad) {
    int o = blockIdx.x * 256 + threadIdx.x;        // 9*128*64 = 73728
    if (o < 9 * 8192) {
        int tap = o >> 13;
        int r   = o & 8191;
        int co  = r >> 6, ci = r & 63;
        wpad[o] = f2bf(W[co * 576 + ci * 9 + tap]);   // W[co][ci][kh][kw]
    }
}

// x-ring: 10 rows x 18 px x 64 ci bf16; pixel px at byte px*128, granule g of
// px stored at slot g ^ ((px>>1)&7) (16B granules) -> conflict-minimal b128.
struct SmemT { unsigned short x[10 * 18 * 64]; };   // 23040 B

// Block: 256 thr = 4 waves (co-quads). Tile = 4 rows x 16 cols x 128 co;
// strip of 8 tiles (32 rows). Weights live in REGISTERS (double-buffered per
// tap from L2-resident wpad) -> no weight LDS, ONE barrier per tile.
__global__ void __launch_bounds__(256, 4)
conv_fused(const float* __restrict__ x,
           const unsigned short* __restrict__ wpad,
           const float* __restrict__ bias,
           float* __restrict__ out)
{
    __shared__ __align__(16) SmemT sm;
    __shared__ float red[4];

    const int tid  = threadIdx.x;
    const int coq  = tid >> 6;        // wave = co quad (32 co)
    const int lane = tid & 63;
    const int lq   = lane >> 4;
    const int lm   = lane & 15;

    const int ct  = blockIdx.x;       // 0..7  col tile (16 wide)
    const int rtg = blockIdx.y;       // 0..3  row strip (32 tall)
    const int n   = blockIdx.z;       // 0..63 image

    const int h0s = rtg * 32;
    const int w0  = ct * 16;
    const float* xn = x + (size_t)n * 1048576;
    const int sbp = h0s % 10;         // ring slot of strip row 0 (slot == h%10)

    // ---------------- prologue: stage x rows h0s..h0s+5 ----------------
    #pragma unroll
    for (int it = 0; it < 2; ++it) {
        int t = it * 256 + tid;
        if (t < 384) {                          // 8 cig * 6 rows * 8 wpairs
            int g = t / 48, rem = t % 48;
            int r = rem >> 3, wq = rem & 7;
            int h = h0s + r;                    // always < 128 (h0s+5 <= 101)
            const float* src = xn + (size_t)(g * 8) * 16384 + h * 128 + (w0 + 2 * wq);
            us8 ua, ub;
            #pragma unroll
            for (int j = 0; j < 8; ++j) {
                float2 v = *(const float2*)(src + j * 16384);
                ua[j] = f2bf(v.x); ub[j] = f2bf(v.y);
            }
            int so = sbp + r; if (so >= 10) so -= 10;
            int px = so * 18 + 2 * wq;
            int key = (px >> 1) & 7;
            char* base = (char*)sm.x + px * 128 + ((g ^ key) << 4);
            *(us8*)(base)       = ua;
            *(us8*)(base + 128) = ub;
        }
    }
    #pragma unroll
    for (int it = 0; it < 2; ++it) {            // halo cols 16,17: 64ci * 6 rows
        int t = it * 256 + tid;
        if (t < 384) {
            int ci = t & 63, r = t >> 6;
            int h = h0s + r;
            float2 v = (w0 + 17 < 128)
                ? *(const float2*)(xn + (size_t)ci * 16384 + h * 128 + w0 + 16)
                : make_float2(0.f, 0.f);
            int so = sbp + r; if (so >= 10) so -= 10;
            int px = so * 18 + 16;
            int key = (px >> 1) & 7;
            unsigned short* p = sm.x + px * 64 + (((ci >> 3) ^ key) << 3) + (ci & 7);
            p[0]  = f2bf(v.x);                  // col 16
            p[64] = f2bf(v.y);                  // col 17 (px+1, same key)
        }
    }

    // per-lane weight base: co = coq*32 + ntl*16 + lm, ci chunk = kc*32 + lq*8
    const char* wb = (const char*)wpad + ((coq * 32 + lm) << 7) + (lq << 4);
    us8 bb[2][4];                               // [parity][ntl*2+kc] dbuf
    #pragma unroll
    for (int f = 0; f < 4; ++f)
        bb[0][f] = *(const us8*)(wb + (f >> 1) * 2048 + (f & 1) * 64);   // tap 0

    float bv[2] = { bias[coq * 32 + lm], bias[coq * 32 + 16 + lm] };

    f32x4 acc[4][2];
    #pragma unroll
    for (int rr = 0; rr < 4; ++rr) {
        acc[rr][0] = (f32x4){0.f, 0.f, 0.f, 0.f};
        acc[rr][1] = (f32x4){0.f, 0.f, 0.f, 0.f};
    }
    float part = 0.0f;

    // per-thread staging task coords (constant across tiles)
    const int sg = tid >> 5, srr = (tid >> 3) & 3, swq = tid & 7;   // main: 256 tasks
    const int hci = tid & 63, hrr = tid >> 6;                       // halo: 256 tasks

    __syncthreads();   // prologue x visible

    int sb = sbp;                               // = hb % 10
    for (int s = 0; s < 8; ++s) {
        const int hb = h0s + s * 4;
        float2 mld[8]; float2 hld;

        // ---- 9 taps, NO barriers; B reg-double-buffered from global ----
        #pragma unroll
        for (int tap = 0; tap < 9; ++tap) {
            const int kh = tap / 3, kw = tap % 3;
            const int tn = (tap + 1 == 9) ? 0 : tap + 1;
            #pragma unroll
            for (int f = 0; f < 4; ++f)         // prefetch next tap's B
                bb[(tap + 1) & 1][f] =
                    *(const us8*)(wb + tn * 16384 + (f >> 1) * 2048 + (f & 1) * 64);

            if (tap == 0 && s < 7) {            // issue next-tile x loads (T14)
                int h = hb + 6 + srr;
                bool ok = h < 128;
                const float* src = xn + (size_t)(sg * 8) * 16384 + h * 128 + (w0 + 2 * swq);
                #pragma unroll
                for (int j = 0; j < 8; ++j)
                    mld[j] = ok ? *(const float2*)(src + j * 16384) : make_float2(0.f, 0.f);
                int hh = hb + 6 + hrr;
                hld = (hh < 128 && w0 + 17 < 128)
                    ? *(const float2*)(xn + (size_t)hci * 16384 + hh * 128 + w0 + 16)
                    : make_float2(0.f, 0.f);
            }

            int q2 = sb + kh; if (q2 >= 10) q2 -= 10;
            #pragma unroll
            for (int kc = 0; kc < 2; ++kc) {
                bf16x8 a[4];
                #pragma unroll
                for (int rr = 0; rr < 4; ++rr) {
                    int so = q2 + rr; if (so >= 10) so -= 10;
                    int px = so * 18 + lm + kw;
                    int slot = ((kc << 2) | lq) ^ ((px >> 1) & 7);
                    a[rr] = *(const bf16x8*)((const char*)sm.x + px * 128 + (slot << 4));
                }
                #pragma unroll
                for (int ntl = 0; ntl < 2; ++ntl) {
                    union { us8 u; bf16x8 b; } bu; bu.u = bb[tap & 1][ntl * 2 + kc];
                    #pragma unroll
                    for (int rr = 0; rr < 4; ++rr)
                        acc[rr][ntl] = __builtin_amdgcn_mfma_f32_16x16x32_bf16(
                            a[rr], bu.b, acc[rr][ntl], 0, 0, 0);
                }
            }
        }

        // ---- write staged rows hb+6..hb+9 (disjoint ring slots) ----
        if (s < 7) {
            us8 ua, ub;
            #pragma unroll
            for (int j = 0; j < 8; ++j) { ua[j] = f2bf(mld[j].x); ub[j] = f2bf(mld[j].y); }
            int q6 = sb + 6; if (q6 >= 10) q6 -= 10;
            int so = q6 + srr; if (so >= 10) so -= 10;
            int px = so * 18 + 2 * swq;
            int key = (px >> 1) & 7;
            char* base = (char*)sm.x + px * 128 + ((sg ^ key) << 4);
            *(us8*)(base)       = ua;
            *(us8*)(base + 128) = ub;
            int so2 = q6 + hrr; if (so2 >= 10) so2 -= 10;
            int px2 = so2 * 18 + 16;
            int key2 = (px2 >> 1) & 7;
            unsigned short* p = sm.x + px2 * 64 + (((hci >> 3) ^ key2) << 3) + (hci & 7);
            p[0]  = f2bf(hld.x);
            p[64] = f2bf(hld.y);
        }

        // tap8 prefetched tap0 into bb[1]; restore parity for next tile
        #pragma unroll
        for (int f = 0; f < 4; ++f) bb[0][f] = bb[1][f];

        // ---- per-tile epilogue: pool + bias + sigmoid ----
        #pragma unroll
        for (int p = 0; p < 2; ++p) {
            int ph = rtg * 16 + s * 2 + p;
            if (ph < 63) {
                int pwb = ct * 8 + lq * 2;
                #pragma unroll
                for (int ntl = 0; ntl < 2; ++ntl) {
                    f32x4 sv = acc[2 * p][ntl] + acc[2 * p + 1][ntl];   // vertical pool
                    float p0 = sv[0] + sv[1];                           // cols (0,1)
                    float p1 = sv[2] + sv[3];                           // cols (2,3)
                    float bbv = bv[ntl];
                    if (pwb < 63)     part += sigf(0.25f * p0 + bbv);
                    if (pwb + 1 < 63) part += sigf(0.25f * p1 + bbv);
                }
            }
        }
        #pragma unroll
        for (int rr = 0; rr < 4; ++rr) {
            acc[rr][0] = (f32x4){0.f, 0.f, 0.f, 0.f};
            acc[rr][1] = (f32x4){0.f, 0.f, 0.f, 0.f};
        }

        sb += 4; if (sb >= 10) sb -= 10;
        __syncthreads();   // staged x visible; ring slots safe to reuse
    }

    // ---- block reduce -> one atomicAdd per block ----
    #pragma unroll
    for (int off = 32; off > 0; off >>= 1)
        part += __shfl_down(part, off, 64);
    if (lane == 0) red[coq] = part;
    __syncthreads();
    if (tid == 0) atomicAdd(&out[n], red[0] + red[1] + red[2] + red[3]);
}

extern "C" void kernel_launch(void* const* d_in, const int* in_sizes, int n_in,
                              void* d_out, int out_size, void* d_ws, size_t ws_size,
                              hipStream_t stream) {
    const float* x = (const float*)d_in[0];
    const float* W = (const float*)d_in[1];
    const float* b = (const float*)d_in[2];
    float* out = (float*)d_out;
    unsigned short* wpad = (unsigned short*)d_ws;   // 147,456 B used

    hipMemsetAsync(d_out, 0, 64 * sizeof(float), stream);
    wxform<<<(9 * 8192 + 255) / 256, 256, 0, stream>>>(W, wpad);
    conv_fused<<<dim3(8, 4, 64), 256, 0, stream>>>(x, wpad, b, out);
}